// Round 3
// baseline (4623.278 us; speedup 1.0000x reference)
//
#include <hip/hip_runtime.h>

#define N_SRC 8192
#define N_DST 4096
#define KNBR 64
#define F_IN 64
#define H1 64
#define F_MSG 128
#define F_OUT 128

// Exact-rounding squared distance, matching numpy's ((dx*dx+dy*dy)+dz*dz)
// with no FMA contraction (argmax/selection must be bit-identical to ref).
__device__ __forceinline__ float d2f(float ax, float ay, float az,
                                     float bx, float by, float bz) {
#pragma clang fp contract(off)
    float dx = ax - bx;
    float dy = ay - by;
    float dz = az - bz;
    return (dx * dx + dy * dy) + dz * dz;
}

// ---------------------------------------------------------------------------
// Kernel 1: farthest point sampling. Single workgroup (serial dependency).
// 512 threads x 16 points in registers. ONE barrier per iteration:
//   key = (distbits << 13) | (8191 ^ idx)  — 64-bit max == argmax with
//   lowest-index tie-break, bit-exact vs numpy.
//   scan(+running u32 bitmax) -> 16-reg rescan -> per-wave DPP u64 max ->
//   lane63 -> wkey[parity][w] -> barrier -> all threads fold 8 keys ->
//   uniform q fetch (readfirstlane/scalar path) -> next scan.
// ---------------------------------------------------------------------------
#define FPS_T 512
#define PPT 16

template <int C>
__device__ __forceinline__ unsigned long long kmax_step(unsigned long long k) {
    // bound_ctrl=true: OOB sources read 0 — identity for u64 max here.
    unsigned lo = (unsigned)__builtin_amdgcn_update_dpp(
        0, (int)(unsigned)k, C, 0xf, 0xf, true);
    unsigned hi = (unsigned)__builtin_amdgcn_update_dpp(
        0, (int)(unsigned)(k >> 32), C, 0xf, 0xf, true);
    unsigned long long o = (((unsigned long long)hi) << 32) | lo;
    return o > k ? o : k;
}

__device__ __forceinline__ unsigned long long wave_max_u64(unsigned long long k) {
    k = kmax_step<0x111>(k);  // row_shr:1
    k = kmax_step<0x112>(k);  // row_shr:2
    k = kmax_step<0x114>(k);  // row_shr:4
    k = kmax_step<0x118>(k);  // row_shr:8
    k = kmax_step<0x142>(k);  // row_bcast:15
    k = kmax_step<0x143>(k);  // row_bcast:31
    return k;                 // valid in lane 63
}

__device__ __forceinline__ unsigned long long u64max(unsigned long long a,
                                                     unsigned long long b) {
    return a > b ? a : b;
}

__global__ __launch_bounds__(FPS_T) void fps_kernel(
    const float* __restrict__ pos, float* __restrict__ pos_dst) {
    __shared__ unsigned long long wkey[2][8];

    const int t = threadIdx.x;
    const int lane = t & 63;
    const int w = t >> 6;

    float px[PPT], py[PPT], pz[PPT], dist[PPT];
    const float x0 = pos[0], y0 = pos[1], z0 = pos[2];
    unsigned bv = 0u;
#pragma unroll
    for (int k = 0; k < PPT; k++) {
        int p = t * PPT + k;
        px[k] = pos[3 * p];
        py[k] = pos[3 * p + 1];
        pz[k] = pos[3 * p + 2];
        dist[k] = d2f(px[k], py[k], pz[k], x0, y0, z0);
        bv = max(bv, __float_as_uint(dist[k]));
    }
    if (t == 0) { pos_dst[0] = x0; pos_dst[1] = y0; pos_dst[2] = z0; }

    // local argmax (lowest k on ties), build key, reduce, stash for i=1
    {
        int bk = 0;
#pragma unroll
        for (int k = PPT - 1; k >= 0; k--)
            if (__float_as_uint(dist[k]) == bv) bk = k;
        unsigned long long key =
            (((unsigned long long)bv) << 13) |
            (unsigned)((t * PPT + bk) ^ 8191);
        key = wave_max_u64(key);
        if (lane == 63) wkey[1][w] = key;
    }

    for (int i = 1; i < N_DST; i++) {
        __syncthreads();  // wkey[i&1] visible to all

        const int p = i & 1;
        unsigned long long g = u64max(
            u64max(u64max(wkey[p][0], wkey[p][1]),
                   u64max(wkey[p][2], wkey[p][3])),
            u64max(u64max(wkey[p][4], wkey[p][5]),
                   u64max(wkey[p][6], wkey[p][7])));

        const int wi =
            __builtin_amdgcn_readfirstlane(((int)(g & 8191ull)) ^ 8191);
        const float qx = pos[3 * wi];
        const float qy = pos[3 * wi + 1];
        const float qz = pos[3 * wi + 2];
        if (t == 0) {
            pos_dst[3 * i] = qx;
            pos_dst[3 * i + 1] = qy;
            pos_dst[3 * i + 2] = qz;
        }

        // paired scalar ops (SLP-friendly for v_pk_*_f32); contraction off.
        bv = 0u;
#pragma unroll
        for (int k = 0; k < PPT; k += 2) {
#pragma clang fp contract(off)
            float dxa = px[k] - qx,     dxb = px[k + 1] - qx;
            float dya = py[k] - qy,     dyb = py[k + 1] - qy;
            float dza = pz[k] - qz,     dzb = pz[k + 1] - qz;
            float sa = dxa * dxa,       sb = dxb * dxb;
            float ta = dya * dya,       tb = dyb * dyb;
            float ua = dza * dza,       ub = dzb * dzb;
            float da = (sa + ta) + ua,  db = (sb + tb) + ub;
            dist[k]     = fminf(dist[k], da);
            dist[k + 1] = fminf(dist[k + 1], db);
            bv = max(bv, __float_as_uint(dist[k]));
            bv = max(bv, __float_as_uint(dist[k + 1]));
        }

        if (i < N_DST - 1) {
            int bk = 0;
#pragma unroll
            for (int k = PPT - 1; k >= 0; k--)
                if (__float_as_uint(dist[k]) == bv) bk = k;
            unsigned long long key =
                (((unsigned long long)bv) << 13) |
                (unsigned)((t * PPT + bk) ^ 8191);
            key = wave_max_u64(key);
            if (lane == 63) wkey[1 - p][w] = key;
        }
    }
}

// ---------------------------------------------------------------------------
// Kernel 2: radius ball query, nearest-64 within r (ties -> lowest index).
// One wave per dst row; candidates pooled in LDS as (d2bits<<13)|idx keys.
// ---------------------------------------------------------------------------
#define POOLCAP 1024

__global__ __launch_bounds__(256) void nbr_kernel(
    const float* __restrict__ pos, const float* __restrict__ pos_dst,
    int* __restrict__ nbr, int* __restrict__ cnt_out) {
    __shared__ unsigned long long pool[4][POOLCAP];
    __shared__ int cnts[4];

    const int t = threadIdx.x;
    const int w = t >> 6;
    const int lane = t & 63;
    const int r = blockIdx.x * 4 + w;

    if (t < 4) cnts[t] = 0;
    __syncthreads();

    const float qx = pos_dst[3 * r];
    const float qy = pos_dst[3 * r + 1];
    const float qz = pos_dst[3 * r + 2];
    // threshold: f32 nearest of (double)0.2*0.2 -> 0.039999999105930328f,
    // matching the reference's weak-typed python-float promotion.
    const float R2 = (float)(0.2 * 0.2);

    for (int p = lane; p < N_SRC; p += 64) {
        float d2 = d2f(pos[3 * p], pos[3 * p + 1], pos[3 * p + 2], qx, qy, qz);
        if (d2 <= R2) {
            int s = atomicAdd(&cnts[w], 1);
            if (s < POOLCAP)
                pool[w][s] =
                    (((unsigned long long)__float_as_uint(d2)) << 13) |
                    (unsigned long long)p;
        }
    }
    __syncthreads();

    int cnt = cnts[w];
    if (cnt > POOLCAP) cnt = POOLCAP;
    const int nsel = cnt < KNBR ? cnt : KNBR;

    int my_nbr = 0;  // default for unused slots (MLP guards by cnt)
    for (int step = 0; step < nsel; step++) {
        unsigned long long best = ~0ull;
        int bs = -1;
        for (int s = lane; s < cnt; s += 64) {
            unsigned long long k = pool[w][s];
            if (k < best) { best = k; bs = s; }
        }
        const unsigned long long lbest = best;
#pragma unroll
        for (int off = 1; off < 64; off <<= 1) {
            unsigned long long o = __shfl_xor(best, off);
            if (o < best) best = o;
        }
        // unique owner (keys contain unique idx) clears its slot
        if (bs >= 0 && lbest == best) pool[w][bs] = ~0ull;
        if (lane == step) my_nbr = (int)(best & 8191ull);
    }
    nbr[r * KNBR + lane] = my_nbr;
    if (lane == 0) cnt_out[r] = nsel;
}

// ---------------------------------------------------------------------------
// Kernel 3: PointConv MLP + masked max aggregate + global linear. f32 VALU.
// 4 rows per block (one wave each), weights staged in LDS.
// ---------------------------------------------------------------------------
__global__ __launch_bounds__(256) void mlp_kernel(
    const float* __restrict__ x, const float* __restrict__ pos,
    const float* __restrict__ pos_dst, const int* __restrict__ nbr,
    const int* __restrict__ cnt_arr, const float* __restrict__ w1,
    const float* __restrict__ b1, const float* __restrict__ w2,
    const float* __restrict__ b2, const float* __restrict__ wg,
    const float* __restrict__ bg, float* __restrict__ y) {
    __shared__ float w1s[67 * 64];
    __shared__ float w2s[64 * 128];
    __shared__ __align__(16) float msgx[4][64];
    __shared__ float rel3[4][4];
    __shared__ __align__(16) float h1s[4][64];
    __shared__ __align__(16) float aggs[4][128];

    const int t = threadIdx.x;
    const int w = t >> 6;
    const int lane = t & 63;
    const int r = blockIdx.x * 4 + w;

    for (int i = t; i < 67 * 64; i += 256) w1s[i] = w1[i];
    for (int i = t; i < 64 * 128; i += 256) w2s[i] = w2[i];
    __syncthreads();

    const int cnt = cnt_arr[r];
    const float pdx = pos_dst[3 * r];
    const float pdy = pos_dst[3 * r + 1];
    const float pdz = pos_dst[3 * r + 2];

    const float bb1 = b1[lane];
    const float bb2a = b2[lane];
    const float bb2b = b2[64 + lane];

    float agg0 = -1e30f, agg1 = -1e30f;

    for (int j = 0; j < KNBR + 1; j++) {
        const bool valid = (j < cnt) || (j == KNBR);
        const int src = (j == KNBR) ? r : ((j < cnt) ? nbr[r * KNBR + j] : 0);

        msgx[w][lane] = x[src * F_IN + lane];
        if (lane < 3) {
            float pv = (lane == 0) ? pdx : ((lane == 1) ? pdy : pdz);
            rel3[w][lane] = pos[3 * src + lane] - pv;
        }
        __syncthreads();

        // h1[lane] = relu(b1 + msg . w1[:,lane])
        float a = bb1;
        const float4* m4 = (const float4*)msgx[w];
#pragma unroll
        for (int k4 = 0; k4 < 16; k4++) {
            float4 m = m4[k4];
            int k = k4 * 4;
            a += m.x * w1s[k * 64 + lane];
            a += m.y * w1s[(k + 1) * 64 + lane];
            a += m.z * w1s[(k + 2) * 64 + lane];
            a += m.w * w1s[(k + 3) * 64 + lane];
        }
        a += rel3[w][0] * w1s[64 * 64 + lane];
        a += rel3[w][1] * w1s[65 * 64 + lane];
        a += rel3[w][2] * w1s[66 * 64 + lane];
        h1s[w][lane] = fmaxf(a, 0.0f);
        __syncthreads();

        // h2[m] for m = lane, lane+64
        float acc0 = bb2a, acc1 = bb2b;
        const float4* h4 = (const float4*)h1s[w];
#pragma unroll
        for (int k4 = 0; k4 < 16; k4++) {
            float4 h = h4[k4];
            int k = k4 * 4;
            acc0 += h.x * w2s[k * 128 + lane];
            acc1 += h.x * w2s[k * 128 + 64 + lane];
            acc0 += h.y * w2s[(k + 1) * 128 + lane];
            acc1 += h.y * w2s[(k + 1) * 128 + 64 + lane];
            acc0 += h.z * w2s[(k + 2) * 128 + lane];
            acc1 += h.z * w2s[(k + 2) * 128 + 64 + lane];
            acc0 += h.w * w2s[(k + 3) * 128 + lane];
            acc1 += h.w * w2s[(k + 3) * 128 + 64 + lane];
        }
        if (valid) {
            agg0 = fmaxf(agg0, acc0);
            agg1 = fmaxf(agg1, acc1);
        }
        __syncthreads();
    }

    aggs[w][lane] = agg0;
    aggs[w][64 + lane] = agg1;
    __syncthreads();

    // y[m] = bg[m] + agg . wg[:,m], m = lane, lane+64 (wg via L2, coalesced)
    float y0 = bg[lane], y1 = bg[64 + lane];
    const float4* a4 = (const float4*)aggs[w];
#pragma unroll
    for (int k4 = 0; k4 < 32; k4++) {
        float4 av = a4[k4];
        int k = k4 * 4;
        y0 += av.x * wg[k * 128 + lane];
        y1 += av.x * wg[k * 128 + 64 + lane];
        y0 += av.y * wg[(k + 1) * 128 + lane];
        y1 += av.y * wg[(k + 1) * 128 + 64 + lane];
        y0 += av.z * wg[(k + 2) * 128 + lane];
        y1 += av.z * wg[(k + 2) * 128 + 64 + lane];
        y0 += av.w * wg[(k + 3) * 128 + lane];
        y1 += av.w * wg[(k + 3) * 128 + 64 + lane];
    }
    y[r * F_OUT + lane] = y0;
    y[r * F_OUT + 64 + lane] = y1;
}

extern "C" void kernel_launch(void* const* d_in, const int* in_sizes, int n_in,
                              void* d_out, int out_size, void* d_ws,
                              size_t ws_size, hipStream_t stream) {
    const float* x   = (const float*)d_in[0];  // [8192,64]
    const float* pos = (const float*)d_in[1];  // [8192,3]
    const float* w1  = (const float*)d_in[2];  // [67,64]
    const float* b1  = (const float*)d_in[3];  // [64]
    const float* w2  = (const float*)d_in[4];  // [64,128]
    const float* b2  = (const float*)d_in[5];  // [128]
    const float* wg  = (const float*)d_in[6];  // [128,128]
    const float* bg  = (const float*)d_in[7];  // [128]
    // d_in[8] = training (always 1 -> K=64)

    float* y = (float*)d_out;                       // [4096,128]
    float* pos_dst = y + N_DST * F_OUT;             // [4096,3]

    int* nbr = (int*)d_ws;                          // [4096,64]
    int* cnt = nbr + N_DST * KNBR;                  // [4096]

    fps_kernel<<<1, FPS_T, 0, stream>>>(pos, pos_dst);
    nbr_kernel<<<N_DST / 4, 256, 0, stream>>>(pos, pos_dst, nbr, cnt);
    mlp_kernel<<<N_DST / 4, 256, 0, stream>>>(x, pos, pos_dst, nbr, cnt, w1,
                                              b1, w2, b2, wg, bg, y);
}

// Round 4
// 4272.686 us; speedup vs baseline: 1.0821x; 1.0821x over previous
//
#include <hip/hip_runtime.h>

#define N_SRC 8192
#define N_DST 4096
#define KNBR 64
#define F_IN 64
#define H1 64
#define F_MSG 128
#define F_OUT 128

typedef float v2f __attribute__((ext_vector_type(2)));

// Exact-rounding squared distance, matching numpy's ((dx*dx+dy*dy)+dz*dz)
// with no FMA contraction (argmax/selection must be bit-identical to ref).
__device__ __forceinline__ float d2f(float ax, float ay, float az,
                                     float bx, float by, float bz) {
#pragma clang fp contract(off)
    float dx = ax - bx;
    float dy = ay - by;
    float dz = az - bz;
    return (dx * dx + dy * dy) + dz * dz;
}

// ---------------------------------------------------------------------------
// Kernel 1: farthest point sampling. Single workgroup (serial dependency).
// 1024 threads x 8 points in registers (float2-packed -> v_pk_add/mul_f32).
// Per iteration (two barriers, all u32):
//   packed scan keeps running u32 bitmax (exact for nonneg f32)
//   -> per-wave DPP u32 max -> lane63 -> wmax[w] -> B1
//   -> all threads fold 16 u32 (ds_read_b128 x4, broadcast)
//   -> threads with bv==gmax rescan 8 regs, atomicMin original index -> B2
//   -> widx -> readfirstlane -> scalar-cache q load -> next scan.
// ---------------------------------------------------------------------------
#define FPS_T 1024
#define PPT 8

__device__ __forceinline__ unsigned wave_max_u32(unsigned x) {
    // gfx9 crosslane sequence; result valid in lane 63. bound_ctrl=true:
    // OOB sources read 0 — identity for nonneg-float bit patterns.
    x = max(x, (unsigned)__builtin_amdgcn_update_dpp(0, (int)x, 0x111, 0xf, 0xf, true)); // row_shr:1
    x = max(x, (unsigned)__builtin_amdgcn_update_dpp(0, (int)x, 0x112, 0xf, 0xf, true)); // row_shr:2
    x = max(x, (unsigned)__builtin_amdgcn_update_dpp(0, (int)x, 0x114, 0xf, 0xf, true)); // row_shr:4
    x = max(x, (unsigned)__builtin_amdgcn_update_dpp(0, (int)x, 0x118, 0xf, 0xf, true)); // row_shr:8
    x = max(x, (unsigned)__builtin_amdgcn_update_dpp(0, (int)x, 0x142, 0xf, 0xf, true)); // row_bcast:15
    x = max(x, (unsigned)__builtin_amdgcn_update_dpp(0, (int)x, 0x143, 0xf, 0xf, true)); // row_bcast:31
    return x;
}

__global__ __launch_bounds__(FPS_T) void fps_kernel(
    const float* __restrict__ pos, float* __restrict__ pos_dst) {
    __shared__ __align__(16) unsigned wmax[16];
    __shared__ unsigned widx[2];

    const int t = threadIdx.x;
    const int lane = t & 63;
    const int w = t >> 6;

    v2f px2[4], py2[4], pz2[4], d2[4];
    const float x0 = pos[0], y0 = pos[1], z0 = pos[2];
    unsigned bv = 0u;
#pragma unroll
    for (int k = 0; k < 4; k++) {
        int p = t * PPT + 2 * k;
        float ax = pos[3 * p], ay = pos[3 * p + 1], az = pos[3 * p + 2];
        float bx = pos[3 * p + 3], by = pos[3 * p + 4], bz = pos[3 * p + 5];
        px2[k] = (v2f){ax, bx};
        py2[k] = (v2f){ay, by};
        pz2[k] = (v2f){az, bz};
        v2f dd;
        dd.x = d2f(ax, ay, az, x0, y0, z0);
        dd.y = d2f(bx, by, bz, x0, y0, z0);
        d2[k] = dd;
        bv = max(bv, max(__float_as_uint(dd.x), __float_as_uint(dd.y)));
    }
    if (t == 0) {
        pos_dst[0] = x0; pos_dst[1] = y0; pos_dst[2] = z0;
        widx[0] = 0xffffffffu;
        widx[1] = 0xffffffffu;
    }

    for (int i = 1; i < N_DST; i++) {
        const unsigned wm = wave_max_u32(bv);
        if (lane == 63) wmax[w] = wm;
        __syncthreads();  // B1: wmax (+init widx on first iter) visible

        const uint4* wm4 = (const uint4*)wmax;
        uint4 a0 = wm4[0], a1 = wm4[1], a2 = wm4[2], a3 = wm4[3];
        unsigned g01 = max(max(a0.x, a0.y), max(a0.z, a0.w));
        unsigned g23 = max(max(a1.x, a1.y), max(a1.z, a1.w));
        unsigned g45 = max(max(a2.x, a2.y), max(a2.z, a2.w));
        unsigned g67 = max(max(a3.x, a3.y), max(a3.z, a3.w));
        const unsigned gmax = max(max(g01, g23), max(g45, g67));

        const int s = i & 1;
        if (t == 0) widx[s ^ 1] = 0xffffffffu;  // slot for next iteration

        if (bv == gmax) {
            int bp = 0;  // lowest matching point within chunk
#pragma unroll
            for (int k = 3; k >= 0; k--) {
                if (__float_as_uint(d2[k].y) == gmax) bp = 2 * k + 1;
                if (__float_as_uint(d2[k].x) == gmax) bp = 2 * k;
            }
            atomicMin(&widx[s], (unsigned)(t * PPT + bp));
        }
        __syncthreads();  // B2: winner final

        const int wi = __builtin_amdgcn_readfirstlane((int)widx[s]);
        const float qx = pos[3 * wi];       // uniform -> scalar cache
        const float qy = pos[3 * wi + 1];
        const float qz = pos[3 * wi + 2];
        if (t == 0) {
            pos_dst[3 * i] = qx;
            pos_dst[3 * i + 1] = qy;
            pos_dst[3 * i + 2] = qz;
        }
        if (i == N_DST - 1) break;

        const v2f qxv = (v2f){qx, qx};
        const v2f qyv = (v2f){qy, qy};
        const v2f qzv = (v2f){qz, qz};
        unsigned nbv = 0u;
#pragma unroll
        for (int k = 0; k < 4; k++) {
#pragma clang fp contract(off)
            v2f dx = px2[k] - qxv;
            v2f dy = py2[k] - qyv;
            v2f dz = pz2[k] - qzv;
            v2f dd = (dx * dx + dy * dy) + dz * dz;
            v2f cur = d2[k];
            v2f mn;
            mn.x = fminf(cur.x, dd.x);
            mn.y = fminf(cur.y, dd.y);
            d2[k] = mn;
            nbv = max(nbv, max(__float_as_uint(mn.x), __float_as_uint(mn.y)));
        }
        bv = nbv;
    }
}

// ---------------------------------------------------------------------------
// Kernel 2: radius ball query, nearest-64 within r (ties -> lowest index).
// One wave per dst row; candidates pooled in LDS as (d2bits<<13)|idx keys.
// ---------------------------------------------------------------------------
#define POOLCAP 1024

__global__ __launch_bounds__(256) void nbr_kernel(
    const float* __restrict__ pos, const float* __restrict__ pos_dst,
    int* __restrict__ nbr, int* __restrict__ cnt_out) {
    __shared__ unsigned long long pool[4][POOLCAP];
    __shared__ int cnts[4];

    const int t = threadIdx.x;
    const int w = t >> 6;
    const int lane = t & 63;
    const int r = blockIdx.x * 4 + w;

    if (t < 4) cnts[t] = 0;
    __syncthreads();

    const float qx = pos_dst[3 * r];
    const float qy = pos_dst[3 * r + 1];
    const float qz = pos_dst[3 * r + 2];
    // threshold: f32 nearest of (double)0.2*0.2 -> 0.039999999105930328f,
    // matching the reference's weak-typed python-float promotion.
    const float R2 = (float)(0.2 * 0.2);

    for (int p = lane; p < N_SRC; p += 64) {
        float d2 = d2f(pos[3 * p], pos[3 * p + 1], pos[3 * p + 2], qx, qy, qz);
        if (d2 <= R2) {
            int s = atomicAdd(&cnts[w], 1);
            if (s < POOLCAP)
                pool[w][s] =
                    (((unsigned long long)__float_as_uint(d2)) << 13) |
                    (unsigned long long)p;
        }
    }
    __syncthreads();

    int cnt = cnts[w];
    if (cnt > POOLCAP) cnt = POOLCAP;
    const int nsel = cnt < KNBR ? cnt : KNBR;

    int my_nbr = 0;  // default for unused slots (MLP guards by cnt)
    for (int step = 0; step < nsel; step++) {
        unsigned long long best = ~0ull;
        int bs = -1;
        for (int s = lane; s < cnt; s += 64) {
            unsigned long long k = pool[w][s];
            if (k < best) { best = k; bs = s; }
        }
        const unsigned long long lbest = best;
#pragma unroll
        for (int off = 1; off < 64; off <<= 1) {
            unsigned long long o = __shfl_xor(best, off);
            if (o < best) best = o;
        }
        // unique owner (keys contain unique idx) clears its slot
        if (bs >= 0 && lbest == best) pool[w][bs] = ~0ull;
        if (lane == step) my_nbr = (int)(best & 8191ull);
    }
    nbr[r * KNBR + lane] = my_nbr;
    if (lane == 0) cnt_out[r] = nsel;
}

// ---------------------------------------------------------------------------
// Kernel 3: PointConv MLP + masked max aggregate + global linear. f32 VALU.
// 4 rows per block (one wave each), weights staged in LDS.
// ---------------------------------------------------------------------------
__global__ __launch_bounds__(256) void mlp_kernel(
    const float* __restrict__ x, const float* __restrict__ pos,
    const float* __restrict__ pos_dst, const int* __restrict__ nbr,
    const int* __restrict__ cnt_arr, const float* __restrict__ w1,
    const float* __restrict__ b1, const float* __restrict__ w2,
    const float* __restrict__ b2, const float* __restrict__ wg,
    const float* __restrict__ bg, float* __restrict__ y) {
    __shared__ float w1s[67 * 64];
    __shared__ float w2s[64 * 128];
    __shared__ __align__(16) float msgx[4][64];
    __shared__ float rel3[4][4];
    __shared__ __align__(16) float h1s[4][64];
    __shared__ __align__(16) float aggs[4][128];

    const int t = threadIdx.x;
    const int w = t >> 6;
    const int lane = t & 63;
    const int r = blockIdx.x * 4 + w;

    for (int i = t; i < 67 * 64; i += 256) w1s[i] = w1[i];
    for (int i = t; i < 64 * 128; i += 256) w2s[i] = w2[i];
    __syncthreads();

    const int cnt = cnt_arr[r];
    const float pdx = pos_dst[3 * r];
    const float pdy = pos_dst[3 * r + 1];
    const float pdz = pos_dst[3 * r + 2];

    const float bb1 = b1[lane];
    const float bb2a = b2[lane];
    const float bb2b = b2[64 + lane];

    float agg0 = -1e30f, agg1 = -1e30f;

    for (int j = 0; j < KNBR + 1; j++) {
        const bool valid = (j < cnt) || (j == KNBR);
        const int src = (j == KNBR) ? r : ((j < cnt) ? nbr[r * KNBR + j] : 0);

        msgx[w][lane] = x[src * F_IN + lane];
        if (lane < 3) {
            float pv = (lane == 0) ? pdx : ((lane == 1) ? pdy : pdz);
            rel3[w][lane] = pos[3 * src + lane] - pv;
        }
        __syncthreads();

        // h1[lane] = relu(b1 + msg . w1[:,lane])
        float a = bb1;
        const float4* m4 = (const float4*)msgx[w];
#pragma unroll
        for (int k4 = 0; k4 < 16; k4++) {
            float4 m = m4[k4];
            int k = k4 * 4;
            a += m.x * w1s[k * 64 + lane];
            a += m.y * w1s[(k + 1) * 64 + lane];
            a += m.z * w1s[(k + 2) * 64 + lane];
            a += m.w * w1s[(k + 3) * 64 + lane];
        }
        a += rel3[w][0] * w1s[64 * 64 + lane];
        a += rel3[w][1] * w1s[65 * 64 + lane];
        a += rel3[w][2] * w1s[66 * 64 + lane];
        h1s[w][lane] = fmaxf(a, 0.0f);
        __syncthreads();

        // h2[m] for m = lane, lane+64
        float acc0 = bb2a, acc1 = bb2b;
        const float4* h4 = (const float4*)h1s[w];
#pragma unroll
        for (int k4 = 0; k4 < 16; k4++) {
            float4 h = h4[k4];
            int k = k4 * 4;
            acc0 += h.x * w2s[k * 128 + lane];
            acc1 += h.x * w2s[k * 128 + 64 + lane];
            acc0 += h.y * w2s[(k + 1) * 128 + lane];
            acc1 += h.y * w2s[(k + 1) * 128 + 64 + lane];
            acc0 += h.z * w2s[(k + 2) * 128 + lane];
            acc1 += h.z * w2s[(k + 2) * 128 + 64 + lane];
            acc0 += h.w * w2s[(k + 3) * 128 + lane];
            acc1 += h.w * w2s[(k + 3) * 128 + 64 + lane];
        }
        if (valid) {
            agg0 = fmaxf(agg0, acc0);
            agg1 = fmaxf(agg1, acc1);
        }
        __syncthreads();
    }

    aggs[w][lane] = agg0;
    aggs[w][64 + lane] = agg1;
    __syncthreads();

    // y[m] = bg[m] + agg . wg[:,m], m = lane, lane+64 (wg via L2, coalesced)
    float y0 = bg[lane], y1 = bg[64 + lane];
    const float4* a4 = (const float4*)aggs[w];
#pragma unroll
    for (int k4 = 0; k4 < 32; k4++) {
        float4 av = a4[k4];
        int k = k4 * 4;
        y0 += av.x * wg[k * 128 + lane];
        y1 += av.x * wg[k * 128 + 64 + lane];
        y0 += av.y * wg[(k + 1) * 128 + lane];
        y1 += av.y * wg[(k + 1) * 128 + 64 + lane];
        y0 += av.z * wg[(k + 2) * 128 + lane];
        y1 += av.z * wg[(k + 2) * 128 + 64 + lane];
        y0 += av.w * wg[(k + 3) * 128 + lane];
        y1 += av.w * wg[(k + 3) * 128 + 64 + lane];
    }
    y[r * F_OUT + lane] = y0;
    y[r * F_OUT + 64 + lane] = y1;
}

extern "C" void kernel_launch(void* const* d_in, const int* in_sizes, int n_in,
                              void* d_out, int out_size, void* d_ws,
                              size_t ws_size, hipStream_t stream) {
    const float* x   = (const float*)d_in[0];  // [8192,64]
    const float* pos = (const float*)d_in[1];  // [8192,3]
    const float* w1  = (const float*)d_in[2];  // [67,64]
    const float* b1  = (const float*)d_in[3];  // [64]
    const float* w2  = (const float*)d_in[4];  // [64,128]
    const float* b2  = (const float*)d_in[5];  // [128]
    const float* wg  = (const float*)d_in[6];  // [128,128]
    const float* bg  = (const float*)d_in[7];  // [128]
    // d_in[8] = training (always 1 -> K=64)

    float* y = (float*)d_out;                       // [4096,128]
    float* pos_dst = y + N_DST * F_OUT;             // [4096,3]

    int* nbr = (int*)d_ws;                          // [4096,64]
    int* cnt = nbr + N_DST * KNBR;                  // [4096]

    fps_kernel<<<1, FPS_T, 0, stream>>>(pos, pos_dst);
    nbr_kernel<<<N_DST / 4, 256, 0, stream>>>(pos, pos_dst, nbr, cnt);
    mlp_kernel<<<N_DST / 4, 256, 0, stream>>>(x, pos, pos_dst, nbr, cnt, w1,
                                              b1, w2, b2, wg, bg, y);
}